// Round 1
// baseline (3613.045 us; speedup 1.0000x reference)
//
#include <hip/hip_runtime.h>

#define NN 50000     // nodes
#define NE 800000    // edges
#define NG 1024      // graphs
#define NP 16384     // pairs
#define NCL 16       // cell lines
#define INCH 64
#define EMB 128
#define HID 256

#define CDIV(a,b) (((a)+(b)-1)/(b))

// ---------------- utility ----------------
__global__ __launch_bounds__(256) void k_set(float* p, int n, float v) {
    int i = blockIdx.x * 256 + threadIdx.x;
    if (i < n) p[i] = v;
}

__global__ __launch_bounds__(256) void k_zero4(float4* p, int n4) {
    int i = blockIdx.x * 256 + threadIdx.x;
    if (i < n4) p[i] = make_float4(0.f, 0.f, 0.f, 0.f);
}

// ---------------- degree / dinv ----------------
__global__ __launch_bounds__(256) void k_deg(const int* __restrict__ col, float* __restrict__ deg) {
    int e = blockIdx.x * 256 + threadIdx.x;
    if (e < NE) atomicAdd(&deg[col[e]], 1.0f);
}

__global__ __launch_bounds__(256) void k_rsqrt(const float* __restrict__ deg, float* __restrict__ dinv) {
    int i = blockIdx.x * 256 + threadIdx.x;
    if (i < NN) dinv[i] = rsqrtf(deg[i]);   // deg >= 1 (self-loop)
}

// ---------------- dense GEMM: Y[M,128] = X[M,K] @ W[K,128] ----------------
// 128 threads, each owns one output column j for 16 rows. W staged in LDS in
// 64-row chunks (32 KB), X rows staged once (<=8 KB).
template<int K>
__global__ __launch_bounds__(128) void gemm_k(const float* __restrict__ X,
                                              const float* __restrict__ W,
                                              float* __restrict__ Y, int M) {
    __shared__ float Ws[64 * 128];
    __shared__ float Xs[16 * K];
    const int j = threadIdx.x;             // output column 0..127
    const int row0 = blockIdx.x * 16;

    for (int i = j; i < 16 * K; i += 128) {
        int r = i / K, k = i - r * K;
        int gr = row0 + r;
        Xs[i] = (gr < M) ? X[(long long)gr * K + k] : 0.f;
    }

    float acc[16];
#pragma unroll
    for (int r = 0; r < 16; ++r) acc[r] = 0.f;

    for (int k0 = 0; k0 < K; k0 += 64) {
        __syncthreads();
        for (int i = j; i < 64 * 128; i += 128)
            Ws[i] = W[(long long)(k0 + (i >> 7)) * 128 + (i & 127)];
        __syncthreads();
#pragma unroll
        for (int r = 0; r < 16; ++r) {
            float a = acc[r];
            const float* xr = &Xs[r * K + k0];
#pragma unroll
            for (int k = 0; k < 64; ++k) a = fmaf(xr[k], Ws[k * 128 + j], a);
            acc[r] = a;
        }
    }
    for (int r = 0; r < 16; ++r) {
        int gr = row0 + r;
        if (gr < M) Y[(long long)gr * 128 + j] = acc[r];
    }
}

// ---------------- edge scatter: AGG[c] += dinv[r]*dinv[c]*HW[r] ----------------
// 32 lanes per edge, 4 features each (float4 gather, 4 scalar atomics).
__global__ __launch_bounds__(256) void k_scatter(const int* __restrict__ rows,
                                                 const int* __restrict__ cols,
                                                 const float* __restrict__ dinv,
                                                 const float* __restrict__ HW,
                                                 float* __restrict__ AGG) {
    long long t = (long long)blockIdx.x * 256 + threadIdx.x;
    int e = (int)(t >> 5);
    if (e >= NE) return;
    int f = ((int)t & 31) * 4;
    int r = rows[e], c = cols[e];
    float w = dinv[r] * dinv[c];
    const float4 v = *reinterpret_cast<const float4*>(&HW[(long long)r * EMB + f]);
    float* dst = &AGG[(long long)c * EMB + f];
    atomicAdd(dst + 0, w * v.x);
    atomicAdd(dst + 1, w * v.y);
    atomicAdd(dst + 2, w * v.z);
    atomicAdd(dst + 3, w * v.w);
}

// ---------------- self-loop + bias + relu (in-place ok: elementwise) ----------------
__global__ __launch_bounds__(256) void k_bias_relu(const float* agg,
                                                   const float* __restrict__ hw,
                                                   const float* __restrict__ dinv,
                                                   const float* __restrict__ bias,
                                                   float* h) {
    int idx = blockIdx.x * 256 + threadIdx.x;
    if (idx >= NN * EMB) return;
    int i = idx >> 7, j = idx & 127;
    float d = dinv[i];
    float v = agg[idx] + d * d * hw[idx] + bias[j];
    h[idx] = v > 0.f ? v : 0.f;
}

// ---------------- mean pool ----------------
__global__ __launch_bounds__(256) void k_pool(const float* __restrict__ H,
                                              const int* __restrict__ batch,
                                              float* __restrict__ gsum,
                                              float* __restrict__ cnt) {
    int idx = blockIdx.x * 256 + threadIdx.x;
    if (idx >= NN * EMB) return;
    int i = idx >> 7, j = idx & 127;
    int g = batch[i];
    atomicAdd(&gsum[g * EMB + j], H[idx]);
    if (j == 0) atomicAdd(&cnt[g], 1.0f);
}

__global__ __launch_bounds__(256) void k_div(float* __restrict__ gsum,
                                             const float* __restrict__ cnt) {
    int idx = blockIdx.x * 256 + threadIdx.x;
    if (idx >= NG * EMB) return;
    int g = idx >> 7;
    float c = cnt[g];
    gsum[idx] /= (c > 1.f ? c : 1.f);
}

// ---------------- per-pair regressor (selected cell line only) ----------------
// One block (256 thr) per pair. Thread t computes hidden unit t, then block
// reduces h * W2 to the scalar output.
__global__ __launch_bounds__(256) void k_reg(const float* __restrict__ GE,
                                             const int* __restrict__ ddb,
                                             const int* __restrict__ ecl,
                                             const float* __restrict__ W1,
                                             const float* __restrict__ B1,
                                             const float* __restrict__ W2,
                                             const float* __restrict__ B2,
                                             float* __restrict__ out) {
    const int p = blockIdx.x;
    const int t = threadIdx.x;
    __shared__ float pr[2 * EMB];
    __shared__ float red[4];
    const int a = ddb[p];            // drug_drug_batch[0][p]
    const int b = ddb[NP + p];       // drug_drug_batch[1][p]
    const int c = ecl[p];
    if (t < EMB) pr[t] = GE[a * EMB + t];
    else         pr[t] = GE[b * EMB + (t - EMB)];
    __syncthreads();

    const float* w1 = &W1[(long long)c * HID * HID];   // [256 in][256 hid]
    float acc = B1[c * HID + t];
#pragma unroll 8
    for (int k = 0; k < 2 * EMB; ++k) acc = fmaf(pr[k], w1[k * HID + t], acc);
    acc = acc > 0.f ? acc : 0.f;

    float contrib = acc * W2[c * HID + t];
    for (int off = 32; off; off >>= 1) contrib += __shfl_down(contrib, off, 64);
    int wave = t >> 6, lane = t & 63;
    if (lane == 0) red[wave] = contrib;
    __syncthreads();
    if (t == 0) out[p] = red[0] + red[1] + red[2] + red[3] + B2[c];
}

// ---------------- launch ----------------
extern "C" void kernel_launch(void* const* d_in, const int* in_sizes, int n_in,
                              void* d_out, int out_size, void* d_ws, size_t ws_size,
                              hipStream_t stream) {
    const float* x    = (const float*)d_in[0];
    const float* c1w  = (const float*)d_in[1];
    const float* c1b  = (const float*)d_in[2];
    const float* c2w  = (const float*)d_in[3];
    const float* c2b  = (const float*)d_in[4];
    const float* rw1  = (const float*)d_in[5];
    const float* rb1  = (const float*)d_in[6];
    const float* rw2  = (const float*)d_in[7];
    const float* rb2  = (const float*)d_in[8];
    const int*   eidx = (const int*)d_in[9];    // [2, NE]: rows then cols
    const int*   batch= (const int*)d_in[10];
    const int*   ddb  = (const int*)d_in[11];   // [2, NP]
    const int*   ecl  = (const int*)d_in[12];
    float* out = (float*)d_out;

    float* ws   = (float*)d_ws;
    float* deg  = ws;                    // NN
    float* dinv = ws + 50048;            // NN
    float* bufA = ws + 100096;           // NN*EMB = 6.4M
    float* bufB = bufA + NN * EMB;       // NN*EMB
    float* gsum = bufB + NN * EMB;       // NG*EMB
    float* cnt  = gsum + NG * EMB;       // NG  (contiguous with gsum)

    const int* erow = eidx;
    const int* ecol = eidx + NE;

    // degree + dinv
    k_set<<<CDIV(NN,256),256,0,stream>>>(deg, NN, 1.0f);   // self-loop
    k_deg<<<CDIV(NE,256),256,0,stream>>>(ecol, deg);
    k_rsqrt<<<CDIV(NN,256),256,0,stream>>>(deg, dinv);

    // layer 1: hw = x@W1 ; agg = scatter ; h1 = relu(agg + dinv^2*hw + b1)
    gemm_k<INCH><<<CDIV(NN,16),128,0,stream>>>(x, c1w, bufA, NN);
    k_zero4<<<CDIV(NN*EMB/4,256),256,0,stream>>>((float4*)bufB, NN*EMB/4);
    k_scatter<<<CDIV(NE*32,256),256,0,stream>>>(erow, ecol, dinv, bufA, bufB);
    k_bias_relu<<<CDIV(NN*EMB,256),256,0,stream>>>(bufB, bufA, dinv, c1b, bufB);

    // layer 2
    gemm_k<EMB><<<CDIV(NN,16),128,0,stream>>>(bufB, c2w, bufA, NN);
    k_zero4<<<CDIV(NN*EMB/4,256),256,0,stream>>>((float4*)bufB, NN*EMB/4);
    k_scatter<<<CDIV(NE*32,256),256,0,stream>>>(erow, ecol, dinv, bufA, bufB);
    k_bias_relu<<<CDIV(NN*EMB,256),256,0,stream>>>(bufB, bufA, dinv, c2b, bufB);

    // mean pool (gsum and cnt are contiguous: zero both in one shot)
    k_zero4<<<CDIV((NG*EMB+NG)/4,256),256,0,stream>>>((float4*)gsum, (NG*EMB+NG)/4);
    k_pool<<<CDIV(NN*EMB,256),256,0,stream>>>(bufB, batch, gsum, cnt);
    k_div<<<CDIV(NG*EMB,256),256,0,stream>>>(gsum, cnt);

    // regressor: only the selected cell line per pair
    k_reg<<<NP,256,0,stream>>>(gsum, ddb, ecl, rw1, rb1, rw2, rb2, out);
}

// Round 2
// 1098.700 us; speedup vs baseline: 3.2885x; 3.2885x over previous
//
#include <hip/hip_runtime.h>

#define NN 50000     // nodes
#define NE 800000    // edges
#define NG 1024      // graphs
#define NP 16384     // pairs
#define NCL 16       // cell lines
#define INCH 64
#define EMB 128
#define HID 256

#define CDIV(a,b) (((a)+(b)-1)/(b))
#define SCAN_BLOCKS CDIV(NN,256)   // 196

// ---------------- small utils ----------------
__global__ __launch_bounds__(256) void k_zeroi(int* p, int n) {
    int i = blockIdx.x * 256 + threadIdx.x;
    if (i < n) p[i] = 0;
}

// ---------------- degree / dinv ----------------
__global__ __launch_bounds__(256) void k_deg(const int* __restrict__ col, int* __restrict__ deg) {
    int e = blockIdx.x * 256 + threadIdx.x;
    if (e < NE) atomicAdd(&deg[col[e]], 1);
}

__global__ __launch_bounds__(256) void k_dinv(const int* __restrict__ deg, float* __restrict__ dinv) {
    int i = blockIdx.x * 256 + threadIdx.x;
    if (i < NN) dinv[i] = rsqrtf((float)(deg[i] + 1));   // +1 self-loop
}

// ---------------- exclusive scan of deg -> off (3-kernel hierarchical) ----------------
__device__ __forceinline__ int block_excl_scan_256(int v, int t, int* incl_out) {
    int lane = t & 63, w = t >> 6;
    int s = v;
#pragma unroll
    for (int d = 1; d < 64; d <<= 1) {
        int u = __shfl_up(s, d, 64);
        if (lane >= d) s += u;
    }
    __shared__ int wsum[4];
    if (lane == 63) wsum[w] = s;
    __syncthreads();
    int add = 0;
    for (int k = 0; k < w; ++k) add += wsum[k];
    int incl = s + add;
    *incl_out = incl;
    return incl - v;   // exclusive
}

__global__ __launch_bounds__(256) void k_scan1(const int* __restrict__ deg,
                                               int* __restrict__ off,
                                               int* __restrict__ bsums) {
    int b = blockIdx.x, t = threadIdx.x;
    int i = b * 256 + t;
    int v = (i < NN) ? deg[i] : 0;
    int incl;
    int excl = block_excl_scan_256(v, t, &incl);
    if (i < NN) off[i] = excl;
    if (t == 255) bsums[b] = incl;
}

__global__ __launch_bounds__(256) void k_scan2(int* __restrict__ bsums) {
    int t = threadIdx.x;
    int v = (t < SCAN_BLOCKS) ? bsums[t] : 0;
    int incl;
    int excl = block_excl_scan_256(v, t, &incl);
    __syncthreads();
    if (t < SCAN_BLOCKS) bsums[t] = excl;
}

__global__ __launch_bounds__(256) void k_scan3(int* __restrict__ off,
                                               const int* __restrict__ bsums) {
    int b = blockIdx.x, t = threadIdx.x;
    int i = b * 256 + t;
    if (i < NN) off[i] += bsums[b];
}

// ---------------- CSR fill: srows grouped by target ----------------
// After this kernel, off[c] == end offset of node c (start[c] = off[c-1], start[0]=0).
__global__ __launch_bounds__(256) void k_fill(const int* __restrict__ rows,
                                              const int* __restrict__ cols,
                                              int* __restrict__ off,
                                              int* __restrict__ srows) {
    int e = blockIdx.x * 256 + threadIdx.x;
    if (e >= NE) return;
    int c = cols[e];
    int pos = atomicAdd(&off[c], 1);
    srows[pos] = rows[e];
}

// ---------------- dense GEMM: Y[M,128] = X[M,K] @ W[K,128] ----------------
template<int K>
__global__ __launch_bounds__(128) void gemm_k(const float* __restrict__ X,
                                              const float* __restrict__ W,
                                              float* __restrict__ Y, int M) {
    __shared__ float Ws[64 * 128];
    __shared__ float Xs[16 * K];
    const int j = threadIdx.x;
    const int row0 = blockIdx.x * 16;

    for (int i = j; i < 16 * K; i += 128) {
        int r = i / K, k = i - r * K;
        int gr = row0 + r;
        Xs[i] = (gr < M) ? X[(long long)gr * K + k] : 0.f;
    }

    float acc[16];
#pragma unroll
    for (int r = 0; r < 16; ++r) acc[r] = 0.f;

    for (int k0 = 0; k0 < K; k0 += 64) {
        __syncthreads();
        for (int i = j; i < 64 * 128; i += 128)
            Ws[i] = W[(long long)(k0 + (i >> 7)) * 128 + (i & 127)];
        __syncthreads();
#pragma unroll
        for (int r = 0; r < 16; ++r) {
            float a = acc[r];
            const float* xr = &Xs[r * K + k0];
#pragma unroll
            for (int k = 0; k < 64; ++k) a = fmaf(xr[k], Ws[k * 128 + j], a);
            acc[r] = a;
        }
    }
    for (int r = 0; r < 16; ++r) {
        int gr = row0 + r;
        if (gr < M) Y[(long long)gr * 128 + j] = acc[r];
    }
}

// ---------------- fused gather + self-loop + bias + relu ----------------
// One wave per target node; lane l owns features [2l, 2l+1].
// out[c] = relu( dinv[c]*(sum_e dinv[r]*hw[r] + dinv[c]*hw[c]) + bias )
__global__ __launch_bounds__(256) void k_gather(const int* __restrict__ off,
                                                const int* __restrict__ srows,
                                                const float* __restrict__ dinv,
                                                const float* __restrict__ HW,
                                                const float* __restrict__ bias,
                                                float* __restrict__ Hout) {
    int node = blockIdx.x * 4 + (threadIdx.x >> 6);
    int lane = threadIdx.x & 63;
    if (node >= NN) return;
    int beg = node ? off[node - 1] : 0;
    int end = off[node];
    float di = dinv[node];
    const float2* HW2 = (const float2*)HW;
    float2 self = HW2[node * 64 + lane];
    float ax = di * self.x, ay = di * self.y;
    int e = beg;
    for (; e + 1 < end; e += 2) {
        int r0 = srows[e], r1 = srows[e + 1];
        float w0 = dinv[r0], w1 = dinv[r1];
        float2 v0 = HW2[r0 * 64 + lane];
        float2 v1 = HW2[r1 * 64 + lane];
        ax = fmaf(w0, v0.x, ax); ay = fmaf(w0, v0.y, ay);
        ax = fmaf(w1, v1.x, ax); ay = fmaf(w1, v1.y, ay);
    }
    if (e < end) {
        int r = srows[e];
        float w = dinv[r];
        float2 v = HW2[r * 64 + lane];
        ax = fmaf(w, v.x, ax); ay = fmaf(w, v.y, ay);
    }
    const float2* B2 = (const float2*)bias;
    float2 b = B2[lane];
    float ox = fmaf(di, ax, b.x);
    float oy = fmaf(di, ay, b.y);
    float2 o = make_float2(ox > 0.f ? ox : 0.f, oy > 0.f ? oy : 0.f);
    *reinterpret_cast<float2*>(&Hout[(long long)node * 128 + lane * 2]) = o;
}

// ---------------- graph starts (batch is sorted) ----------------
__global__ __launch_bounds__(256) void k_gstart(const int* __restrict__ batch,
                                                int* __restrict__ gstart) {
    int g = blockIdx.x * 256 + threadIdx.x;
    if (g > NG) return;
    int lo = 0, hi = NN;
    while (lo < hi) {
        int m = (lo + hi) >> 1;
        if (batch[m] < g) lo = m + 1; else hi = m;
    }
    gstart[g] = lo;
}

// ---------------- mean pool: contiguous segment reduction ----------------
__global__ __launch_bounds__(128) void k_pool2(const float* __restrict__ H,
                                               const int* __restrict__ gstart,
                                               float* __restrict__ gsum) {
    int g = blockIdx.x;
    int j = threadIdx.x;
    int s = gstart[g], e = gstart[g + 1];
    float acc = 0.f;
    for (int i = s; i < e; ++i) acc += H[(long long)i * 128 + j];
    float c = (float)(e - s);
    gsum[g * 128 + j] = acc / fmaxf(c, 1.f);
}

// ---------------- per-pair regressor (selected cell line only) ----------------
__global__ __launch_bounds__(256) void k_reg(const float* __restrict__ GE,
                                             const int* __restrict__ ddb,
                                             const int* __restrict__ ecl,
                                             const float* __restrict__ W1,
                                             const float* __restrict__ B1,
                                             const float* __restrict__ W2,
                                             const float* __restrict__ B2,
                                             float* __restrict__ out) {
    const int p = blockIdx.x;
    const int t = threadIdx.x;
    __shared__ float pr[2 * EMB];
    __shared__ float red[4];
    const int a = ddb[p];
    const int b = ddb[NP + p];
    const int c = ecl[p];
    if (t < EMB) pr[t] = GE[a * EMB + t];
    else         pr[t] = GE[b * EMB + (t - EMB)];
    __syncthreads();

    const float* w1 = &W1[(long long)c * HID * HID];
    float acc = B1[c * HID + t];
#pragma unroll 8
    for (int k = 0; k < 2 * EMB; ++k) acc = fmaf(pr[k], w1[k * HID + t], acc);
    acc = acc > 0.f ? acc : 0.f;

    float contrib = acc * W2[c * HID + t];
    for (int off = 32; off; off >>= 1) contrib += __shfl_down(contrib, off, 64);
    int wave = t >> 6, lane = t & 63;
    if (lane == 0) red[wave] = contrib;
    __syncthreads();
    if (t == 0) out[p] = red[0] + red[1] + red[2] + red[3] + B2[c];
}

// ---------------- launch ----------------
extern "C" void kernel_launch(void* const* d_in, const int* in_sizes, int n_in,
                              void* d_out, int out_size, void* d_ws, size_t ws_size,
                              hipStream_t stream) {
    const float* x    = (const float*)d_in[0];
    const float* c1w  = (const float*)d_in[1];
    const float* c1b  = (const float*)d_in[2];
    const float* c2w  = (const float*)d_in[3];
    const float* c2b  = (const float*)d_in[4];
    const float* rw1  = (const float*)d_in[5];
    const float* rb1  = (const float*)d_in[6];
    const float* rw2  = (const float*)d_in[7];
    const float* rb2  = (const float*)d_in[8];
    const int*   eidx = (const int*)d_in[9];    // [2, NE]: rows then cols
    const int*   batch= (const int*)d_in[10];
    const int*   ddb  = (const int*)d_in[11];   // [2, NP]
    const int*   ecl  = (const int*)d_in[12];
    float* out = (float*)d_out;

    // ---- workspace layout (4-byte units) ----
    // persistent: off(NN) | srows(NE) | dinv(NN) | bufA(6.4M) | bufB(6.4M)
    // transient aliases inside bufA before gemm1: degi(NN), bsums(256)
    // transient aliases inside bufA after gather2: gsum(NG*EMB), gstart(NG+1)
    char* w8 = (char*)d_ws;
    int*   off   = (int*)w8;                          // NN      -> pad 50048
    int*   srows = off + 50048;                       // NE
    float* dinv  = (float*)(srows + NE);              // NN      -> pad 50048
    float* bufA  = dinv + 50048;                      // NN*EMB
    float* bufB  = bufA + NN * EMB;                   // NN*EMB

    int*   degi   = (int*)bufA;                       // transient (pre-gemm1)
    int*   bsums  = degi + 50048;                     // transient (pre-gemm1)
    float* gsum   = bufA;                             // transient (post-gather2)
    int*   gstart = (int*)(bufA + NG * EMB);          // transient (post-gather2)

    const int* erow = eidx;
    const int* ecol = eidx + NE;

    // ---- CSR build ----
    k_zeroi<<<CDIV(NN,256),256,0,stream>>>(degi, NN);
    k_deg<<<CDIV(NE,256),256,0,stream>>>(ecol, degi);
    k_dinv<<<CDIV(NN,256),256,0,stream>>>(degi, dinv);
    k_scan1<<<SCAN_BLOCKS,256,0,stream>>>(degi, off, bsums);
    k_scan2<<<1,256,0,stream>>>(bsums);
    k_scan3<<<SCAN_BLOCKS,256,0,stream>>>(off, bsums);
    k_fill<<<CDIV(NE,256),256,0,stream>>>(erow, ecol, off, srows);
    // off[c] now holds END offsets; start[c] = off[c-1] (start[0]=0).

    // ---- layer 1: hw = x@W1 ; h1 = relu(dinv*(gather + dinv*hw) + b1) ----
    gemm_k<INCH><<<CDIV(NN,16),128,0,stream>>>(x, c1w, bufA, NN);
    k_gather<<<CDIV(NN,4),256,0,stream>>>(off, srows, dinv, bufA, c1b, bufB);

    // ---- layer 2 ----
    gemm_k<EMB><<<CDIV(NN,16),128,0,stream>>>(bufB, c2w, bufA, NN);
    k_gather<<<CDIV(NN,4),256,0,stream>>>(off, srows, dinv, bufA, c2b, bufB);
    // bufA dead -> reuse for gsum/gstart

    // ---- mean pool over sorted batch ----
    k_gstart<<<CDIV(NG+1,256),256,0,stream>>>(batch, gstart);
    k_pool2<<<NG,128,0,stream>>>(bufB, gstart, gsum);

    // ---- regressor: only the selected cell line per pair ----
    k_reg<<<NP,256,0,stream>>>(gsum, ddb, ecl, rw1, rb1, rw2, rb2, out);
}

// Round 3
// 362.532 us; speedup vs baseline: 9.9661x; 3.0306x over previous
//
#include <hip/hip_runtime.h>

#define NN 50000     // nodes
#define NE 800000    // edges
#define NG 1024      // graphs
#define NP 16384     // pairs
#define NCL 16       // cell lines
#define INCH 64
#define EMB 128
#define HID 256

#define CDIV(a,b) (((a)+(b)-1)/(b))
#define SCAN_BLOCKS CDIV(NN,256)   // 196

// ---------------- small utils ----------------
__global__ __launch_bounds__(256) void k_zeroi(int* p, int n) {
    int i = blockIdx.x * 256 + threadIdx.x;
    if (i < n) p[i] = 0;
}

// ---------------- degree / dinv ----------------
__global__ __launch_bounds__(256) void k_deg(const int* __restrict__ col, int* __restrict__ deg) {
    int e = blockIdx.x * 256 + threadIdx.x;
    if (e < NE) atomicAdd(&deg[col[e]], 1);
}

__global__ __launch_bounds__(256) void k_dinv(const int* __restrict__ deg, float* __restrict__ dinv) {
    int i = blockIdx.x * 256 + threadIdx.x;
    if (i < NN) dinv[i] = rsqrtf((float)(deg[i] + 1));   // +1 self-loop
}

// ---------------- exclusive scan of deg -> off ----------------
__device__ __forceinline__ int block_excl_scan_256(int v, int t, int* incl_out) {
    int lane = t & 63, w = t >> 6;
    int s = v;
#pragma unroll
    for (int d = 1; d < 64; d <<= 1) {
        int u = __shfl_up(s, d, 64);
        if (lane >= d) s += u;
    }
    __shared__ int wsum[4];
    if (lane == 63) wsum[w] = s;
    __syncthreads();
    int add = 0;
    for (int k = 0; k < w; ++k) add += wsum[k];
    int incl = s + add;
    *incl_out = incl;
    return incl - v;
}

__global__ __launch_bounds__(256) void k_scan1(const int* __restrict__ deg,
                                               int* __restrict__ off,
                                               int* __restrict__ bsums) {
    int b = blockIdx.x, t = threadIdx.x;
    int i = b * 256 + t;
    int v = (i < NN) ? deg[i] : 0;
    int incl;
    int excl = block_excl_scan_256(v, t, &incl);
    if (i < NN) off[i] = excl;
    if (t == 255) bsums[b] = incl;
}

__global__ __launch_bounds__(256) void k_scan2(int* __restrict__ bsums) {
    int t = threadIdx.x;
    int v = (t < SCAN_BLOCKS) ? bsums[t] : 0;
    int incl;
    int excl = block_excl_scan_256(v, t, &incl);
    __syncthreads();
    if (t < SCAN_BLOCKS) bsums[t] = excl;
}

__global__ __launch_bounds__(256) void k_scan3(int* __restrict__ off,
                                               const int* __restrict__ bsums) {
    int b = blockIdx.x, t = threadIdx.x;
    int i = b * 256 + t;
    if (i < NN) off[i] += bsums[b];
}

// ---------------- CSR fill ----------------
__global__ __launch_bounds__(256) void k_fill(const int* __restrict__ rows,
                                              const int* __restrict__ cols,
                                              int* __restrict__ off,
                                              int* __restrict__ srows) {
    int e = blockIdx.x * 256 + threadIdx.x;
    if (e >= NE) return;
    int c = cols[e];
    int pos = atomicAdd(&off[c], 1);
    srows[pos] = rows[e];
}

// ---------------- GEMM: Y[M,128] = X[M,K] @ W[K,128], reg-tiled ----------------
// 256 thr: block = 32 rows x 128 cols; thread = 4r x 4c; KC=32.
template<int K>
__global__ __launch_bounds__(256) void gemm32(const float* __restrict__ X,
                                              const float* __restrict__ W,
                                              float* __restrict__ Y, int M) {
    __shared__ float Xt[32][36];    // [k][row], padded to keep 16B-aligned f4
    __shared__ float Wsh[32][128];  // [k][col]
    const int t  = threadIdx.x;
    const int tr = t >> 5;          // 0..7  -> rows 4tr..4tr+3
    const int tc = t & 31;          // 0..31 -> cols 4tc..4tc+3
    const int row0 = blockIdx.x * 32;
    const int rr = t >> 3, kq = t & 7;   // staging coords

    float acc[4][4];
#pragma unroll
    for (int i = 0; i < 4; ++i)
#pragma unroll
        for (int j = 0; j < 4; ++j) acc[i][j] = 0.f;

    const float4* X4 = (const float4*)X;
    const float4* W4 = (const float4*)W;
    float4* Ws4 = (float4*)&Wsh[0][0];

    for (int k0 = 0; k0 < K; k0 += 32) {
        __syncthreads();
        // X tile (32 rows x 32 k), transposed into Xt[k][row]
        int gr = row0 + rr;
        float4 xv = (gr < M) ? X4[(gr * K + k0 + 4 * kq) >> 2]
                             : make_float4(0.f, 0.f, 0.f, 0.f);
        Xt[4 * kq + 0][rr] = xv.x;
        Xt[4 * kq + 1][rr] = xv.y;
        Xt[4 * kq + 2][rr] = xv.z;
        Xt[4 * kq + 3][rr] = xv.w;
        // W tile (32 k x 128 cols), contiguous
#pragma unroll
        for (int i = t; i < 32 * 32; i += 256)
            Ws4[i] = W4[(k0 + (i >> 5)) * 32 + (i & 31)];
        __syncthreads();
#pragma unroll 4
        for (int k = 0; k < 32; ++k) {
            float4 xf = *reinterpret_cast<const float4*>(&Xt[k][4 * tr]);
            float4 wf = *reinterpret_cast<const float4*>(&Wsh[k][4 * tc]);
            float xs[4] = {xf.x, xf.y, xf.z, xf.w};
            float ws[4] = {wf.x, wf.y, wf.z, wf.w};
#pragma unroll
            for (int i = 0; i < 4; ++i)
#pragma unroll
                for (int j = 0; j < 4; ++j)
                    acc[i][j] = fmaf(xs[i], ws[j], acc[i][j]);
        }
    }
    float4* Y4 = (float4*)Y;
#pragma unroll
    for (int i = 0; i < 4; ++i) {
        int gr = row0 + 4 * tr + i;
        if (gr < M)
            Y4[gr * 32 + tc] = make_float4(acc[i][0], acc[i][1], acc[i][2], acc[i][3]);
    }
}

// ---------------- fused gather + self-loop + bias + relu ----------------
__global__ __launch_bounds__(256) void k_gather(const int* __restrict__ off,
                                                const int* __restrict__ srows,
                                                const float* __restrict__ dinv,
                                                const float* __restrict__ HW,
                                                const float* __restrict__ bias,
                                                float* __restrict__ Hout) {
    int node = blockIdx.x * 4 + (threadIdx.x >> 6);
    int lane = threadIdx.x & 63;
    if (node >= NN) return;
    int beg = node ? off[node - 1] : 0;
    int end = off[node];
    float di = dinv[node];
    const float2* HW2 = (const float2*)HW;
    float2 self = HW2[node * 64 + lane];
    float ax = di * self.x, ay = di * self.y;
    int e = beg;
    for (; e + 1 < end; e += 2) {
        int r0 = srows[e], r1 = srows[e + 1];
        float w0 = dinv[r0], w1 = dinv[r1];
        float2 v0 = HW2[r0 * 64 + lane];
        float2 v1 = HW2[r1 * 64 + lane];
        ax = fmaf(w0, v0.x, ax); ay = fmaf(w0, v0.y, ay);
        ax = fmaf(w1, v1.x, ax); ay = fmaf(w1, v1.y, ay);
    }
    if (e < end) {
        int r = srows[e];
        float w = dinv[r];
        float2 v = HW2[r * 64 + lane];
        ax = fmaf(w, v.x, ax); ay = fmaf(w, v.y, ay);
    }
    const float2* B2 = (const float2*)bias;
    float2 b = B2[lane];
    float ox = fmaf(di, ax, b.x);
    float oy = fmaf(di, ay, b.y);
    float2 o = make_float2(ox > 0.f ? ox : 0.f, oy > 0.f ? oy : 0.f);
    *reinterpret_cast<float2*>(&Hout[(long long)node * 128 + lane * 2]) = o;
}

// ---------------- graph starts (batch is sorted) ----------------
__global__ __launch_bounds__(256) void k_gstart(const int* __restrict__ batch,
                                                int* __restrict__ gstart) {
    int g = blockIdx.x * 256 + threadIdx.x;
    if (g > NG) return;
    int lo = 0, hi = NN;
    while (lo < hi) {
        int m = (lo + hi) >> 1;
        if (batch[m] < g) lo = m + 1; else hi = m;
    }
    gstart[g] = lo;
}

// ---------------- mean pool ----------------
__global__ __launch_bounds__(128) void k_pool2(const float* __restrict__ H,
                                               const int* __restrict__ gstart,
                                               float* __restrict__ gsum) {
    int g = blockIdx.x;
    int j = threadIdx.x;
    int s = gstart[g], e = gstart[g + 1];
    float acc = 0.f;
    for (int i = s; i < e; ++i) acc += H[(long long)i * 128 + j];
    float c = (float)(e - s);
    gsum[g * 128 + j] = acc / fmaxf(c, 1.f);
}

// ---------------- batched GEMM: AB[z][g][t] = GE @ W1-half ----------------
// z = c*2 + part : part 0 -> rows 0..127 of W1[c] (ga half), part 1 -> rows 128..255.
// grid (32 rowblks, 2 col panels, 32 batches). M=1024, K=128, N=256.
__global__ __launch_bounds__(256) void gemm_bat(const float* __restrict__ GE,
                                                const float* __restrict__ W1,
                                                float* __restrict__ AB) {
    __shared__ float Xt[32][36];
    __shared__ float Wsh[32][128];
    const int t  = threadIdx.x;
    const int tr = t >> 5, tc = t & 31;
    const int row0 = blockIdx.x * 32;
    const int y = blockIdx.y;           // col panel (0/1)
    const int z = blockIdx.z;           // batch
    const int rr = t >> 3, kq = t & 7;

    const float* Wbase = W1 + (z >> 1) * (HID * HID) + (z & 1) * (128 * HID) + y * 128;

    float acc[4][4];
#pragma unroll
    for (int i = 0; i < 4; ++i)
#pragma unroll
        for (int j = 0; j < 4; ++j) acc[i][j] = 0.f;

    const float4* X4 = (const float4*)GE;
    float4* Ws4 = (float4*)&Wsh[0][0];

    for (int k0 = 0; k0 < 128; k0 += 32) {
        __syncthreads();
        float4 xv = X4[((row0 + rr) * 128 + k0 + 4 * kq) >> 2];
        Xt[4 * kq + 0][rr] = xv.x;
        Xt[4 * kq + 1][rr] = xv.y;
        Xt[4 * kq + 2][rr] = xv.z;
        Xt[4 * kq + 3][rr] = xv.w;
        const float4* Wc4 = (const float4*)(Wbase + k0 * HID);
#pragma unroll
        for (int i = t; i < 32 * 32; i += 256)
            Ws4[i] = Wc4[(i >> 5) * 64 + (i & 31)];
        __syncthreads();
#pragma unroll 4
        for (int k = 0; k < 32; ++k) {
            float4 xf = *reinterpret_cast<const float4*>(&Xt[k][4 * tr]);
            float4 wf = *reinterpret_cast<const float4*>(&Wsh[k][4 * tc]);
            float xs[4] = {xf.x, xf.y, xf.z, xf.w};
            float ws[4] = {wf.x, wf.y, wf.z, wf.w};
#pragma unroll
            for (int i = 0; i < 4; ++i)
#pragma unroll
                for (int j = 0; j < 4; ++j)
                    acc[i][j] = fmaf(xs[i], ws[j], acc[i][j]);
        }
    }
    float4* O4 = (float4*)AB;
#pragma unroll
    for (int i = 0; i < 4; ++i) {
        int g = row0 + 4 * tr + i;
        O4[((z * NG + g) * HID + y * 128) / 4 + tc] =
            make_float4(acc[i][0], acc[i][1], acc[i][2], acc[i][3]);
    }
}

// ---------------- pair epilogue ----------------
// out[p] = B2[c] + sum_t relu(A[c][ga][t] + B[c][gb][t] + B1[c][t]) * W2[c][t]
__global__ __launch_bounds__(256) void k_pair(const float* __restrict__ AB,
                                              const int* __restrict__ ddb,
                                              const int* __restrict__ ecl,
                                              const float* __restrict__ B1,
                                              const float* __restrict__ W2,
                                              const float* __restrict__ B2,
                                              float* __restrict__ out) {
    int p = blockIdx.x * 4 + (threadIdx.x >> 6);
    int lane = threadIdx.x & 63;
    int c = ecl[p];
    int a = ddb[p];
    int b = ddb[NP + p];
    const float4* rA = (const float4*)&AB[((c * 2 + 0) * NG + a) * HID];
    const float4* rB = (const float4*)&AB[((c * 2 + 1) * NG + b) * HID];
    const float4* b1 = (const float4*)&B1[c * HID];
    const float4* w2 = (const float4*)&W2[c * HID];
    float4 va = rA[lane], vb = rB[lane], v1 = b1[lane], v2 = w2[lane];
    float hx = va.x + vb.x + v1.x;
    float hy = va.y + vb.y + v1.y;
    float hz = va.z + vb.z + v1.z;
    float hw = va.w + vb.w + v1.w;
    float s = 0.f;
    s = fmaf(hx > 0.f ? hx : 0.f, v2.x, s);
    s = fmaf(hy > 0.f ? hy : 0.f, v2.y, s);
    s = fmaf(hz > 0.f ? hz : 0.f, v2.z, s);
    s = fmaf(hw > 0.f ? hw : 0.f, v2.w, s);
    for (int o = 32; o; o >>= 1) s += __shfl_down(s, o, 64);
    if (lane == 0) out[p] = s + B2[c];
}

// ---------------- launch ----------------
extern "C" void kernel_launch(void* const* d_in, const int* in_sizes, int n_in,
                              void* d_out, int out_size, void* d_ws, size_t ws_size,
                              hipStream_t stream) {
    const float* x    = (const float*)d_in[0];
    const float* c1w  = (const float*)d_in[1];
    const float* c1b  = (const float*)d_in[2];
    const float* c2w  = (const float*)d_in[3];
    const float* c2b  = (const float*)d_in[4];
    const float* rw1  = (const float*)d_in[5];
    const float* rb1  = (const float*)d_in[6];
    const float* rw2  = (const float*)d_in[7];
    const float* rb2  = (const float*)d_in[8];
    const int*   eidx = (const int*)d_in[9];    // [2, NE]: rows then cols
    const int*   batch= (const int*)d_in[10];
    const int*   ddb  = (const int*)d_in[11];   // [2, NP]
    const int*   ecl  = (const int*)d_in[12];
    float* out = (float*)d_out;

    // ---- workspace layout (floats) ----
    // off(50048) | srows(NE) | dinv(50048) | bufA(6.4M) | bufB(6.4M)
    // transient in bufA pre-gemm1: degi, bsums
    // transient in srows post-gather2: gsum(NG*EMB), gstart(NG+1)
    // transient over bufA+bufB post-pool: AB (32*NG*HID = 8.39M floats)
    int*   off   = (int*)d_ws;
    int*   srows = off + 50048;
    float* dinv  = (float*)(srows + NE);
    float* bufA  = dinv + 50048;
    float* bufB  = bufA + NN * EMB;

    int*   degi   = (int*)bufA;
    int*   bsums  = degi + 50048;
    float* gsum   = (float*)srows;                  // alive only after gather2
    int*   gstart = srows + NG * EMB;
    float* AB     = bufA;                           // alive only after pool

    const int* erow = eidx;
    const int* ecol = eidx + NE;

    // ---- CSR build ----
    k_zeroi<<<CDIV(NN,256),256,0,stream>>>(degi, NN);
    k_deg<<<CDIV(NE,256),256,0,stream>>>(ecol, degi);
    k_dinv<<<CDIV(NN,256),256,0,stream>>>(degi, dinv);
    k_scan1<<<SCAN_BLOCKS,256,0,stream>>>(degi, off, bsums);
    k_scan2<<<1,256,0,stream>>>(bsums);
    k_scan3<<<SCAN_BLOCKS,256,0,stream>>>(off, bsums);
    k_fill<<<CDIV(NE,256),256,0,stream>>>(erow, ecol, off, srows);

    // ---- layer 1 ----
    gemm32<INCH><<<CDIV(NN,32),256,0,stream>>>(x, c1w, bufA, NN);
    k_gather<<<CDIV(NN,4),256,0,stream>>>(off, srows, dinv, bufA, c1b, bufB);

    // ---- layer 2 ----
    gemm32<EMB><<<CDIV(NN,32),256,0,stream>>>(bufB, c2w, bufA, NN);
    k_gather<<<CDIV(NN,4),256,0,stream>>>(off, srows, dinv, bufA, c2b, bufB);

    // ---- mean pool (srows/off/dinv dead from here; gsum aliases srows) ----
    k_gstart<<<CDIV(NG+1,256),256,0,stream>>>(batch, gstart);
    k_pool2<<<NG,128,0,stream>>>(bufB, gstart, gsum);

    // ---- regressor: precompute GE @ W1 halves for all 16 lines ----
    dim3 bgrid(NG/32, 2, 2*NCL);
    gemm_bat<<<bgrid,256,0,stream>>>(gsum, rw1, AB);
    k_pair<<<NP/4,256,0,stream>>>(AB, ddb, ecl, rb1, rw2, rb2, out);
}

// Round 4
// 305.922 us; speedup vs baseline: 11.8103x; 1.1850x over previous
//
#include <hip/hip_runtime.h>

#define NN 50000     // nodes
#define NE 800000    // edges
#define NG 1024      // graphs
#define NP 16384     // pairs
#define NCL 16       // cell lines
#define INCH 64
#define EMB 128
#define HID 256

#define CDIV(a,b) (((a)+(b)-1)/(b))
#define SCAN_BLOCKS CDIV(NN,256)   // 196

// ---------------- small utils ----------------
__global__ __launch_bounds__(256) void k_zeroi(int* p, int n) {
    int i = blockIdx.x * 256 + threadIdx.x;
    if (i < n) p[i] = 0;
}

__global__ __launch_bounds__(256) void k_deg(const int* __restrict__ col, int* __restrict__ deg) {
    int e = blockIdx.x * 256 + threadIdx.x;
    if (e < NE) atomicAdd(&deg[col[e]], 1);
}

// ---------------- exclusive scan of deg -> off (+ dinv fused) ----------------
__device__ __forceinline__ int block_excl_scan_256(int v, int t, int* incl_out) {
    int lane = t & 63, w = t >> 6;
    int s = v;
#pragma unroll
    for (int d = 1; d < 64; d <<= 1) {
        int u = __shfl_up(s, d, 64);
        if (lane >= d) s += u;
    }
    __shared__ int wsum[4];
    if (lane == 63) wsum[w] = s;
    __syncthreads();
    int add = 0;
    for (int k = 0; k < w; ++k) add += wsum[k];
    int incl = s + add;
    *incl_out = incl;
    return incl - v;
}

__global__ __launch_bounds__(256) void k_scan1(const int* __restrict__ deg,
                                               int* __restrict__ off,
                                               int* __restrict__ bsums,
                                               float* __restrict__ dinv) {
    int b = blockIdx.x, t = threadIdx.x;
    int i = b * 256 + t;
    int v = (i < NN) ? deg[i] : 0;
    int incl;
    int excl = block_excl_scan_256(v, t, &incl);
    if (i < NN) {
        off[i] = excl;
        dinv[i] = rsqrtf((float)(v + 1));   // +1 self-loop
    }
    if (t == 255) bsums[b] = incl;
}

__global__ __launch_bounds__(256) void k_scan2(int* __restrict__ bsums) {
    int t = threadIdx.x;
    int v = (t < SCAN_BLOCKS) ? bsums[t] : 0;
    int incl;
    int excl = block_excl_scan_256(v, t, &incl);
    __syncthreads();
    if (t < SCAN_BLOCKS) bsums[t] = excl;
}

__global__ __launch_bounds__(256) void k_scan3(int* __restrict__ off,
                                               const int* __restrict__ bsums) {
    int b = blockIdx.x, t = threadIdx.x;
    int i = b * 256 + t;
    if (i < NN) off[i] += bsums[b];
}

// ---------------- CSR fill ----------------
__global__ __launch_bounds__(256) void k_fill(const int* __restrict__ rows,
                                              const int* __restrict__ cols,
                                              int* __restrict__ off,
                                              int* __restrict__ srows) {
    int e = blockIdx.x * 256 + threadIdx.x;
    if (e >= NE) return;
    int c = cols[e];
    int pos = atomicAdd(&off[c], 1);
    srows[pos] = rows[e];
}

// ---------------- gather: DST[c] = dinv[c]*(sum_e dinv[r]*SRC[r] + dinv[c]*SRC[c]) ----------------
// wave = 1 node; 4 edge slots x 16 feature lanes (float4 each). FEAT in {64,128}.
template<int FEAT>
__global__ __launch_bounds__(256) void k_gath(const int* __restrict__ off,
                                              const int* __restrict__ srows,
                                              const float* __restrict__ dinv,
                                              const float* __restrict__ SRC,
                                              float* __restrict__ DST) {
    constexpr int NV4 = FEAT / 4;     // float4s per row
    constexpr int PL  = NV4 / 16;     // float4s per lane (1 or 2)
    int node = blockIdx.x * 4 + (threadIdx.x >> 6);
    int lane = threadIdx.x & 63;
    int s = lane >> 4, q = lane & 15;
    int beg = node ? off[node - 1] : 0;
    int end = off[node];
    float di = dinv[node];
    const float4* S4 = (const float4*)SRC;

    float4 acc[PL];
#pragma unroll
    for (int i = 0; i < PL; ++i) acc[i] = make_float4(0.f, 0.f, 0.f, 0.f);
    if (s == 0) {
#pragma unroll
        for (int i = 0; i < PL; ++i) {
            float4 v = S4[node * NV4 + i * 16 + q];
            acc[i] = make_float4(di * v.x, di * v.y, di * v.z, di * v.w);
        }
    }
    for (int e0 = beg; e0 < end; e0 += 4) {
        int e = e0 + s;
        if (e < end) {
            int r = srows[e];
            float w = dinv[r];
#pragma unroll
            for (int i = 0; i < PL; ++i) {
                float4 v = S4[r * NV4 + i * 16 + q];
                acc[i].x = fmaf(w, v.x, acc[i].x);
                acc[i].y = fmaf(w, v.y, acc[i].y);
                acc[i].z = fmaf(w, v.z, acc[i].z);
                acc[i].w = fmaf(w, v.w, acc[i].w);
            }
        }
    }
    // reduce over the 4 edge slots (xor on lane bits 4,5)
#pragma unroll
    for (int d = 16; d < 64; d <<= 1) {
#pragma unroll
        for (int i = 0; i < PL; ++i) {
            acc[i].x += __shfl_xor(acc[i].x, d, 64);
            acc[i].y += __shfl_xor(acc[i].y, d, 64);
            acc[i].z += __shfl_xor(acc[i].z, d, 64);
            acc[i].w += __shfl_xor(acc[i].w, d, 64);
        }
    }
    if (lane < 16) {
        float4* D4 = (float4*)DST;
#pragma unroll
        for (int i = 0; i < PL; ++i) {
            float4 o = make_float4(di * acc[i].x, di * acc[i].y,
                                   di * acc[i].z, di * acc[i].w);
            D4[node * NV4 + i * 16 + lane] = o;
        }
    }
}

// ---------------- GEMM: Y[M,128] = X[M,K] @ W[K,128] (+bias,relu) ----------------
// 256 thr: block = 32 rows x 128 cols; thread = 4r x 4c; KC=32.
template<int K, bool EPI>
__global__ __launch_bounds__(256) void gemm32(const float* __restrict__ X,
                                              const float* __restrict__ W,
                                              const float* __restrict__ bias,
                                              float* __restrict__ Y, int M) {
    __shared__ float Xt[32][36];
    __shared__ float Wsh[32][128];
    const int t  = threadIdx.x;
    const int tr = t >> 5;
    const int tc = t & 31;
    const int row0 = blockIdx.x * 32;
    const int rr = t >> 3, kq = t & 7;

    float acc[4][4];
#pragma unroll
    for (int i = 0; i < 4; ++i)
#pragma unroll
        for (int j = 0; j < 4; ++j) acc[i][j] = 0.f;

    const float4* X4 = (const float4*)X;
    const float4* W4 = (const float4*)W;
    float4* Ws4 = (float4*)&Wsh[0][0];

    for (int k0 = 0; k0 < K; k0 += 32) {
        __syncthreads();
        int gr = row0 + rr;
        float4 xv = (gr < M) ? X4[(gr * K + k0 + 4 * kq) >> 2]
                             : make_float4(0.f, 0.f, 0.f, 0.f);
        Xt[4 * kq + 0][rr] = xv.x;
        Xt[4 * kq + 1][rr] = xv.y;
        Xt[4 * kq + 2][rr] = xv.z;
        Xt[4 * kq + 3][rr] = xv.w;
#pragma unroll
        for (int i = t; i < 32 * 32; i += 256)
            Ws4[i] = W4[(k0 + (i >> 5)) * 32 + (i & 31)];
        __syncthreads();
#pragma unroll 4
        for (int k = 0; k < 32; ++k) {
            float4 xf = *reinterpret_cast<const float4*>(&Xt[k][4 * tr]);
            float4 wf = *reinterpret_cast<const float4*>(&Wsh[k][4 * tc]);
            float xs[4] = {xf.x, xf.y, xf.z, xf.w};
            float ws[4] = {wf.x, wf.y, wf.z, wf.w};
#pragma unroll
            for (int i = 0; i < 4; ++i)
#pragma unroll
                for (int j = 0; j < 4; ++j)
                    acc[i][j] = fmaf(xs[i], ws[j], acc[i][j]);
        }
    }
    float4 b = make_float4(0.f, 0.f, 0.f, 0.f);
    if (EPI) b = ((const float4*)bias)[tc];
    float4* Y4 = (float4*)Y;
#pragma unroll
    for (int i = 0; i < 4; ++i) {
        int gr = row0 + 4 * tr + i;
        if (gr < M) {
            float4 o = make_float4(acc[i][0] + b.x, acc[i][1] + b.y,
                                   acc[i][2] + b.z, acc[i][3] + b.w);
            if (EPI) {
                o.x = o.x > 0.f ? o.x : 0.f;
                o.y = o.y > 0.f ? o.y : 0.f;
                o.z = o.z > 0.f ? o.z : 0.f;
                o.w = o.w > 0.f ? o.w : 0.f;
            }
            Y4[gr * 32 + tc] = o;
        }
    }
}

// ---------------- mean pool (gstart search fused) ----------------
__global__ __launch_bounds__(128) void k_pool2(const float* __restrict__ H,
                                               const int* __restrict__ batch,
                                               float* __restrict__ gsum) {
    int g = blockIdx.x;
    __shared__ int se[2];
    if (threadIdx.x < 2) {
        int tgt = g + threadIdx.x;
        int lo = 0, hi = NN;
        while (lo < hi) {
            int m = (lo + hi) >> 1;
            if (batch[m] < tgt) lo = m + 1; else hi = m;
        }
        se[threadIdx.x] = lo;
    }
    __syncthreads();
    int s = se[0], e = se[1];
    int j = threadIdx.x;
    float acc = 0.f;
    for (int i = s; i < e; ++i) acc += H[(long long)i * 128 + j];
    float c = (float)(e - s);
    gsum[g * 128 + j] = acc / fmaxf(c, 1.f);
}

// ---------------- batched GEMM: AB[z][g][t] = GE @ W1-half ----------------
__global__ __launch_bounds__(256) void gemm_bat(const float* __restrict__ GE,
                                                const float* __restrict__ W1,
                                                float* __restrict__ AB) {
    __shared__ float Xt[32][36];
    __shared__ float Wsh[32][128];
    const int t  = threadIdx.x;
    const int tr = t >> 5, tc = t & 31;
    const int row0 = blockIdx.x * 32;
    const int y = blockIdx.y;
    const int z = blockIdx.z;
    const int rr = t >> 3, kq = t & 7;

    const float* Wbase = W1 + (z >> 1) * (HID * HID) + (z & 1) * (128 * HID) + y * 128;

    float acc[4][4];
#pragma unroll
    for (int i = 0; i < 4; ++i)
#pragma unroll
        for (int j = 0; j < 4; ++j) acc[i][j] = 0.f;

    const float4* X4 = (const float4*)GE;
    float4* Ws4 = (float4*)&Wsh[0][0];

    for (int k0 = 0; k0 < 128; k0 += 32) {
        __syncthreads();
        float4 xv = X4[((row0 + rr) * 128 + k0 + 4 * kq) >> 2];
        Xt[4 * kq + 0][rr] = xv.x;
        Xt[4 * kq + 1][rr] = xv.y;
        Xt[4 * kq + 2][rr] = xv.z;
        Xt[4 * kq + 3][rr] = xv.w;
        const float4* Wc4 = (const float4*)(Wbase + k0 * HID);
#pragma unroll
        for (int i = t; i < 32 * 32; i += 256)
            Ws4[i] = Wc4[(i >> 5) * 64 + (i & 31)];
        __syncthreads();
#pragma unroll 4
        for (int k = 0; k < 32; ++k) {
            float4 xf = *reinterpret_cast<const float4*>(&Xt[k][4 * tr]);
            float4 wf = *reinterpret_cast<const float4*>(&Wsh[k][4 * tc]);
            float xs[4] = {xf.x, xf.y, xf.z, xf.w};
            float ws[4] = {wf.x, wf.y, wf.z, wf.w};
#pragma unroll
            for (int i = 0; i < 4; ++i)
#pragma unroll
                for (int j = 0; j < 4; ++j)
                    acc[i][j] = fmaf(xs[i], ws[j], acc[i][j]);
        }
    }
    float4* O4 = (float4*)AB;
#pragma unroll
    for (int i = 0; i < 4; ++i) {
        int g = row0 + 4 * tr + i;
        O4[((z * NG + g) * HID + y * 128) / 4 + tc] =
            make_float4(acc[i][0], acc[i][1], acc[i][2], acc[i][3]);
    }
}

// ---------------- pair epilogue ----------------
__global__ __launch_bounds__(256) void k_pair(const float* __restrict__ AB,
                                              const int* __restrict__ ddb,
                                              const int* __restrict__ ecl,
                                              const float* __restrict__ B1,
                                              const float* __restrict__ W2,
                                              const float* __restrict__ B2,
                                              float* __restrict__ out) {
    int p = blockIdx.x * 4 + (threadIdx.x >> 6);
    int lane = threadIdx.x & 63;
    int c = ecl[p];
    int a = ddb[p];
    int b = ddb[NP + p];
    const float4* rA = (const float4*)&AB[((c * 2 + 0) * NG + a) * HID];
    const float4* rB = (const float4*)&AB[((c * 2 + 1) * NG + b) * HID];
    const float4* b1 = (const float4*)&B1[c * HID];
    const float4* w2 = (const float4*)&W2[c * HID];
    float4 va = rA[lane], vb = rB[lane], v1 = b1[lane], v2 = w2[lane];
    float hx = va.x + vb.x + v1.x;
    float hy = va.y + vb.y + v1.y;
    float hz = va.z + vb.z + v1.z;
    float hw = va.w + vb.w + v1.w;
    float s = 0.f;
    s = fmaf(hx > 0.f ? hx : 0.f, v2.x, s);
    s = fmaf(hy > 0.f ? hy : 0.f, v2.y, s);
    s = fmaf(hz > 0.f ? hz : 0.f, v2.z, s);
    s = fmaf(hw > 0.f ? hw : 0.f, v2.w, s);
    for (int o = 32; o; o >>= 1) s += __shfl_down(s, o, 64);
    if (lane == 0) out[p] = s + B2[c];
}

// ---------------- launch ----------------
extern "C" void kernel_launch(void* const* d_in, const int* in_sizes, int n_in,
                              void* d_out, int out_size, void* d_ws, size_t ws_size,
                              hipStream_t stream) {
    const float* x    = (const float*)d_in[0];
    const float* c1w  = (const float*)d_in[1];
    const float* c1b  = (const float*)d_in[2];
    const float* c2w  = (const float*)d_in[3];
    const float* c2b  = (const float*)d_in[4];
    const float* rw1  = (const float*)d_in[5];
    const float* rb1  = (const float*)d_in[6];
    const float* rw2  = (const float*)d_in[7];
    const float* rb2  = (const float*)d_in[8];
    const int*   eidx = (const int*)d_in[9];    // [2, NE]: rows then cols
    const int*   batch= (const int*)d_in[10];
    const int*   ddb  = (const int*)d_in[11];   // [2, NP]
    const int*   ecl  = (const int*)d_in[12];
    float* out = (float*)d_out;

    // ---- workspace layout (floats) ----
    // off(50048) | srows(NE) | dinv(50048) | bufA(NN*128) | bufB(NN*128)
    // transient in bufA pre-gather1: degi, bsums
    // transient in srows post-pool: gsum(NG*EMB)
    // transient over bufA(+into bufB) post-pool: AB (32*NG*HID)
    int*   off   = (int*)d_ws;
    int*   srows = off + 50048;
    float* dinv  = (float*)(srows + NE);
    float* bufA  = dinv + 50048;
    float* bufB  = bufA + NN * EMB;

    int*   degi  = (int*)bufA;
    int*   bsums = degi + 50048;
    float* gsum  = (float*)srows;      // alive only after pool
    float* AB    = bufA;               // alive only after pool

    const int* erow = eidx;
    const int* ecol = eidx + NE;

    // ---- CSR build ----
    k_zeroi<<<CDIV(NN,256),256,0,stream>>>(degi, NN);
    k_deg<<<CDIV(NE,256),256,0,stream>>>(ecol, degi);
    k_scan1<<<SCAN_BLOCKS,256,0,stream>>>(degi, off, bsums, dinv);
    k_scan2<<<1,256,0,stream>>>(bsums);
    k_scan3<<<SCAN_BLOCKS,256,0,stream>>>(off, bsums);
    k_fill<<<CDIV(NE,256),256,0,stream>>>(erow, ecol, off, srows);

    // ---- layer 1: aggX = A_hat @ x ; H1 = relu(aggX @ W1 + b1) ----
    k_gath<INCH><<<CDIV(NN,4),256,0,stream>>>(off, srows, dinv, x, bufA);
    gemm32<INCH,true><<<CDIV(NN,32),256,0,stream>>>(bufA, c1w, c1b, bufB, NN);

    // ---- layer 2: aggH = A_hat @ H1 ; H2 = relu(aggH @ W2 + b2) ----
    k_gath<EMB><<<CDIV(NN,4),256,0,stream>>>(off, srows, dinv, bufB, bufA);
    gemm32<EMB,true><<<CDIV(NN,32),256,0,stream>>>(bufA, c2w, c2b, bufB, NN);

    // ---- mean pool over sorted batch (srows/off/dinv dead; gsum aliases srows) ----
    k_pool2<<<NG,128,0,stream>>>(bufB, batch, gsum);

    // ---- regressor: precompute GE @ W1 halves for all 16 lines ----
    dim3 bgrid(NG/32, 2, 2*NCL);
    gemm_bat<<<bgrid,256,0,stream>>>(gsum, rw1, AB);
    k_pair<<<NP/4,256,0,stream>>>(AB, ddb, ecl, rb1, rw2, rb2, out);
}